// Round 6
// baseline (340.691 us; speedup 1.0000x reference)
//
#include <hip/hip_runtime.h>
#include <math.h>

// LSTM fused: H=32, D=1, B=4096, T=1024 — R18: same-SIMD coupled wave pairs.
//
// R17 closed the model: wall 655 cyc/step = VALU 360 + MFMA 155 + DS 40 +
// ~120 barrier/in-phase stall, still ADDITIVE. One 16x16x32 f16 tile costs
// ~19.4 cyc PER SIMD (m06's 4.85 was per-CU), so 8 tiles/SIMD/step = 155 is
// real work. The pair waves sat on DIFFERENT SIMDs (NT=128), each SIMD
// hosting randomly-phased waves of different blocks -> MFMA and VALU phases
// collide instead of interleaving.
// R18: NT=512, 8 waves, 16 batches. With round-robin placement (wave i ->
// SIMD i%4), waves g and g+4 share a SIMD. P = wv>>2, grp = wv&3: each SIMD
// hosts BOTH halves of one coupled pair. After each barrier both waves
// contend for the MFMA pipe -> pipe serializes -> self-organized anti-phase:
// A's MFMA under B's act-VALU and vice versa. Expected wall ~500-560.
// If placement differs, degrades to R17's random mixing (no regression).
// Everything else identical to R17: parity split u=2n+P, 4 MFMA tiles/wave
// (tau=2g+P), dbuf LDS h exchange (ds_write_b16 / ds_read_b128), rational
// acts with -L/-2L folded, zero extraction acc[g][0].

#define HH 32
#define TT 1024
#define BPB 16              // batches per block (4 per pair-group)
#define NT 512

typedef _Float16 half8 __attribute__((ext_vector_type(8)));
typedef float    f32x4 __attribute__((ext_vector_type(4)));

__global__ __attribute__((amdgpu_flat_work_group_size(NT, NT),
                          amdgpu_waves_per_eu(2, 2)))
void lstm_vp(const float* __restrict__ x,
             const float* __restrict__ W_ih,
             const float* __restrict__ W_hh,
             const float* __restrict__ b_ih,
             const float* __restrict__ b_hh,
             const float* __restrict__ fc_W,
             const float* __restrict__ fc_b,
             float* __restrict__ out)
{
    __shared__ _Float16 xw[BPB * TT];                 // 32 KB: x fp16
    __shared__ __align__(16) _Float16 hx[2][BPB][HH]; // 2 KB: h dbuf
    __shared__ float fo[BPB];                         // epilogue partials

    const int tid  = threadIdx.x;
    const int wv   = tid >> 6;
    const int P    = wv >> 2;            // parity: unit 2n+P
    const int grp  = wv & 3;             // pair group; partner = wv ^ 4
    const int lane = tid & 63;
    const int q    = lane >> 4;          // batch index within group (0..3)
    const int n    = lane & 15;          // unit-pair index (0..15)
    const int u    = 2 * n + P;          // owned unit
    const int bq   = grp * 4 + q;        // batch within block
    const int gb0  = blockIdx.x * BPB;

    // ---- stage the block's 16 x-rows into LDS as fp16 (all waves) ----
    {
        const float4* xg = (const float4*)(x + (size_t)gb0 * TT);
        #pragma unroll
        for (int it = 0; it < (BPB * TT / 4) / NT; ++it) {
            const int idx = it * NT + tid;
            const float4 v = xg[idx];
            _Float16* dst = &xw[idx * 4];
            dst[0] = (_Float16)v.x; dst[1] = (_Float16)v.y;
            dst[2] = (_Float16)v.z; dst[3] = (_Float16)v.w;
        }
    }

    const float L1 = 1.4426950408889634f;    // log2(e)

    // ---- B-fragments: this wave's parity tiles only (tau = 2g+P).
    //      Col n = W_hh row 32g+2n+P; lane supplies B[k=8q+j][n].
    //      Pre-scaled by -L (i,f,o) / -2L (g). ----
    half8 wf[4];
    #pragma unroll
    for (int g = 0; g < 4; ++g) {
        const float s = (g == 2) ? -2.0f * L1 : -L1;
        const float* arow = W_hh + (size_t)(32 * g + 2 * n + P) * HH + 8 * q;
        #pragma unroll
        for (int j = 0; j < 8; ++j)
            wf[g][j] = (_Float16)(arow[j] * s);
    }

    // ---- per-lane act constants for the single owned unit u ----
    float wx[4], bb[4];
    #pragma unroll
    for (int g = 0; g < 4; ++g) {
        const float s = (g == 2) ? -2.0f * L1 : -L1;
        wx[g] = W_ih[g * HH + u] * s;
        bb[g] = (b_ih[g * HH + u] + b_hh[g * HH + u]) * s;
    }

    // zero h slot 0 (each lane covers its own state) + staging sync
    hx[0][bq][u] = (_Float16)0.0f;
    __syncthreads();

    // A-frag read pointers: units 8q..8q+7 of batch grp*4 + (n>>2)
    const half8* hr0 = (const half8*)&hx[0][grp * 4 + (n >> 2)][8 * q];
    const half8* hr1 = (const half8*)&hx[1][grp * 4 + (n >> 2)][8 * q];

    float c = 0.0f, h = 0.0f;

    const half8* xp = (const half8*)&xw[bq * TT];
    half8 xcur = xp[0];

    #pragma unroll 1
    for (int tc = 0; tc < TT / 8; ++tc) {
        const half8 xv8 = xcur;
        xcur = xp[(tc + 1) & (TT / 8 - 1)];   // prefetch next chunk (off-chain)

        // pre-convert the chunk to f32 once (off the serial chain)
        float xf[8];
        #pragma unroll
        for (int j = 0; j < 8; ++j) xf[j] = (float)xv8[j];

        #pragma unroll
        for (int tt = 0; tt < 8; ++tt) {
            // ---- A-frag: one ds_read_b128 from current slot ----
            const half8 av = (tt & 1) ? *hr1 : *hr0;

            // ---- preact input part, OFF the chain ----
            const float xv = xf[tt];
            float qq[4];
            #pragma unroll
            for (int g = 0; g < 4; ++g)
                qq[g] = fmaf(xv, wx[g], bb[g]);

            const f32x4 zero = {0.0f, 0.0f, 0.0f, 0.0f};
            f32x4 acc[4];
            #pragma unroll
            for (int g = 0; g < 4; ++g) {
                acc[g] = __builtin_amdgcn_mfma_f32_16x16x32_f16(
                             av, wf[g], zero, 0, 0, 0);
                asm("" : "+v"(acc[g]));   // pin quad to arch VGPRs
            }

            // ---- exp2 args, fixed element 0: zero extraction ----
            const float ea = __builtin_amdgcn_exp2f(acc[0][0] + qq[0]); // e^-i
            const float eb = __builtin_amdgcn_exp2f(acc[1][0] + qq[1]); // e^-f
            const float ed = __builtin_amdgcn_exp2f(acc[2][0] + qq[2]); // e^-2g
            const float ee = __builtin_amdgcn_exp2f(acc[3][0] + qq[3]); // e^-o

            // ---- c' = (c*u*v + w*(2-v)) / (u*v*w); one rcp ----
            const float uu = 1.0f + ea, vv = 1.0f + ed, ww = 1.0f + eb;
            const float uv  = uu * vv;
            const float num = fmaf(c, uv, ww * (2.0f - vv));
            c = num * __builtin_amdgcn_rcpf(uv * ww);

            // ---- h = (1-m)/((1+e)(1+m)); guard only the m-overflow ----
            const float marg = fminf(c * (-2.0f * L1), 126.0f);
            const float m = __builtin_amdgcn_exp2f(marg);
            h = (1.0f - m) * __builtin_amdgcn_rcpf((1.0f + ee) * (1.0f + m));

            // ---- publish h for next step, flip slot, sync ----
            hx[(tt & 1) ^ 1][bq][u] = (_Float16)h;
            __syncthreads();
        }
    }

    // ---- epilogue: out[gb0+bq] = fc_W . h + fc_b across the parity pair ----
    float pr = h * fc_W[u];
    pr += __shfl_xor(pr, 1, 64);
    pr += __shfl_xor(pr, 2, 64);
    pr += __shfl_xor(pr, 4, 64);
    pr += __shfl_xor(pr, 8, 64);
    if (P == 1 && n == 0) fo[bq] = pr;
    __syncthreads();
    if (P == 0 && n == 0)
        out[gb0 + bq] = pr + fo[bq] + fc_b[0];
}

extern "C" void kernel_launch(void* const* d_in, const int* in_sizes, int n_in,
                              void* d_out, int out_size, void* d_ws, size_t ws_size,
                              hipStream_t stream) {
    const float* x    = (const float*)d_in[0];
    const float* W_ih = (const float*)d_in[1];
    const float* W_hh = (const float*)d_in[2];
    const float* b_ih = (const float*)d_in[3];
    const float* b_hh = (const float*)d_in[4];
    const float* fc_W = (const float*)d_in[5];
    const float* fc_b = (const float*)d_in[6];
    float* out = (float*)d_out;

    const int B = in_sizes[0] / TT;   // 4096 (D == 1)
    dim3 grid(B / BPB), block(NT);
    lstm_vp<<<grid, block, 0, stream>>>(x, W_ih, W_hh, b_ih, b_hh,
                                        fc_W, fc_b, out);
}